// Round 5
// baseline (30.521 us; speedup 1.0000x reference)
//
#include <hip/hip_runtime.h>

#define NBINS 100
#define NATOM 1024
#define NBLK  256
#define NWAVE 16
#define HPAD  124            // 7 under + 100 bins + 17 over: kills all bound checks
#define PI_F 3.14159265358979323846f

// 256 blocks x 1024 threads; block handles rows i0..i0+3, thread owns column j.
// Windowed Gaussian smear, 16 bins starting at floor(d/DB)-7.
// exp-recurrence: g_k = exp(coeff*(t0-k*DB)^2) => g_{k+1} = g_k * B * D_k,
//   B = exp((99/5)*t0), D_k = exp(-0.5*(2k+1))  (compile-time constants).
// Per-wave padded LDS hist (no bounds checks, ds_add_f32 with imm offsets).
// Block partials -> ws[bin*NBLK + block]; no global atomics, no pre-zeroing.
__global__ __launch_bounds__(1024) void rdf_hist(const float* __restrict__ xyz,
                                                 const float* __restrict__ cell,
                                                 float* __restrict__ ws) {
    const float cx = cell[0], cy = cell[1], cz = cell[2];
    const float hx = 0.5f * cx, hy = 0.5f * cy, hz = 0.5f * cz;
    const float coeff  = -0.5f * (99.0f * 99.0f) / (5.0f * 5.0f);  // -196.02
    const float cutsq  = 5.5f * 5.5f;
    const float DB     = 5.0f / 99.0f;
    const float INV_DB = 99.0f / 5.0f;
    const float B_SLOPE = 99.0f / 5.0f;        // -2*coeff*DB, exact

    // D_k = exp(-0.5*(2k+1)), k = 0..14
    const float D0 = 6.0653065971e-01f, D1 = 2.2313016014e-01f,
                D2 = 8.2084998624e-02f, D3 = 3.0197383422e-02f,
                D4 = 1.1108996538e-02f, D5 = 4.0867714385e-03f,
                D6 = 1.5034391930e-03f, D7 = 5.5308437015e-04f,
                D8 = 2.0346836901e-04f, D9 = 7.4851829888e-05f,
                D10 = 2.7536449349e-05f, D11 = 1.0130093587e-05f,
                D12 = 3.7266531720e-06f, D13 = 1.3709590863e-06f,
                D14 = 5.0434766256e-07f;

    __shared__ float shw[NWAVE][HPAD];
    for (int k = threadIdx.x; k < NWAVE * HPAD; k += 1024)
        (&shw[0][0])[k] = 0.0f;
    __syncthreads();

    const int wave = threadIdx.x >> 6;

    // thread owns atom j (coalesced load)
    const int j = threadIdx.x;
    const float xj = xyz[3 * j + 0];
    const float yj = xyz[3 * j + 1];
    const float zj = xyz[3 * j + 2];

    const int i0 = blockIdx.x * (NATOM / NBLK);
#pragma unroll
    for (int r = 0; r < NATOM / NBLK; ++r) {
        const int i = i0 + r;                 // block-uniform -> scalar loads
        const float xi = xyz[3 * i + 0];
        const float yi = xyz[3 * i + 1];
        const float zi = xyz[3 * i + 2];
        float dx = xj - xi;                   // dvec = xyz[j] - xyz[i]
        float dy = yj - yi;
        float dz = zj - zi;
        // minimum-image PBC, exact replication of reference shift rule
        dx += (dx < -hx ? cx : 0.0f) - (dx >= hx ? cx : 0.0f);
        dy += (dy < -hy ? cy : 0.0f) - (dy >= hy ? cy : 0.0f);
        dz += (dz < -hz ? cz : 0.0f) - (dz >= hz ? cz : 0.0f);
        const float dsq = dx * dx + dy * dy + dz * dz;
        if (dsq != 0.0f && dsq < cutsq) {
            const float d    = sqrtf(dsq);
            const int   base = (int)(d * INV_DB) - 7;   // window [base, base+15]
            const float t0   = d - (float)base * DB;
            float g = __expf(coeff * t0 * t0);          // g_0
            const float B = __expf(B_SLOPE * t0);
            float* h = &shw[wave][base + 7];            // base+7 in [0, 102]
            atomicAdd(&h[0],  g);  g *= B * D0;
            atomicAdd(&h[1],  g);  g *= B * D1;
            atomicAdd(&h[2],  g);  g *= B * D2;
            atomicAdd(&h[3],  g);  g *= B * D3;
            atomicAdd(&h[4],  g);  g *= B * D4;
            atomicAdd(&h[5],  g);  g *= B * D5;
            atomicAdd(&h[6],  g);  g *= B * D6;
            atomicAdd(&h[7],  g);  g *= B * D7;
            atomicAdd(&h[8],  g);  g *= B * D8;
            atomicAdd(&h[9],  g);  g *= B * D9;
            atomicAdd(&h[10], g);  g *= B * D10;
            atomicAdd(&h[11], g);  g *= B * D11;
            atomicAdd(&h[12], g);  g *= B * D12;
            atomicAdd(&h[13], g);  g *= B * D13;
            atomicAdd(&h[14], g);  g *= B * D14;
            atomicAdd(&h[15], g);
        }
    }

    __syncthreads();
    if (threadIdx.x < NBINS) {
        float s = 0.0f;
#pragma unroll
        for (int w = 0; w < NWAVE; ++w) s += shw[w][threadIdx.x + 7];
        // bin-major partial store: finalize's loads over blocks are coalesced
        ws[threadIdx.x * NBLK + blockIdx.x] = s;
    }
}

// single block, 1024 threads: reduce 256 partials/bin, normalize, emit outputs
__global__ __launch_bounds__(1024) void rdf_finalize(const float* __restrict__ ws,
                                                     float* __restrict__ out) {
    __shared__ float tot[NBINS];
    __shared__ float wsum[2];

    const int t = threadIdx.x;
    if (t < 8 * NBINS) {             // 8 threads per bin
        const int b = t >> 3, sub = t & 7;
        const float* p = &ws[b * NBLK + sub * 32];
        float s0 = 0.f, s1 = 0.f, s2 = 0.f, s3 = 0.f;
#pragma unroll
        for (int k = 0; k < 32; k += 4) {
            s0 += p[k + 0]; s1 += p[k + 1]; s2 += p[k + 2]; s3 += p[k + 3];
        }
        float s = (s0 + s1) + (s2 + s3);
        s += __shfl_xor(s, 1, 64);   // butterfly within the 8-lane group
        s += __shfl_xor(s, 2, 64);
        s += __shfl_xor(s, 4, 64);
        if (sub == 0) tot[b] = s;
    }
    __syncthreads();

    const float v = (t < NBINS) ? tot[t] : 0.0f;
    if (t < 128) {
        float s = v;
        s += __shfl_xor(s, 1, 64);
        s += __shfl_xor(s, 2, 64);
        s += __shfl_xor(s, 4, 64);
        s += __shfl_xor(s, 8, 64);
        s += __shfl_xor(s, 16, 64);
        s += __shfl_xor(s, 32, 64);
        if ((t & 63) == 0) wsum[t >> 6] = s;
    }
    __syncthreads();
    const float total = wsum[0] + wsum[1];

    if (t < NBINS) {
        const float count = v / total;
        out[t] = count;                                   // output 0: count[100]
        const float b0 = 0.05f * (float)t;
        const float b1 = 0.05f * (float)(t + 1);
        const float vol = (4.0f * PI_F / 3.0f) * (b1 * b1 * b1 - b0 * b0 * b0);
        const float V = (4.0f / 3.0f) * PI_F * 125.0f;    // end^3 = 5^3
        out[2 * NBINS + 1 + t] = count * V / vol;         // output 2: rdf[100]
    }
    if (t < NBINS + 1) {
        out[NBINS + t] = 0.05f * (float)t;                // output 1: bins[101]
    }
}

extern "C" void kernel_launch(void* const* d_in, const int* in_sizes, int n_in,
                              void* d_out, int out_size, void* d_ws, size_t ws_size,
                              hipStream_t stream) {
    const float* xyz  = (const float*)d_in[0];
    const float* cell = (const float*)d_in[1];
    float* out = (float*)d_out;
    float* ws  = (float*)d_ws;

    rdf_hist<<<NBLK, 1024, 0, stream>>>(xyz, cell, ws);
    rdf_finalize<<<1, 1024, 0, stream>>>(ws, out);
}

// Round 6
// 21.131 us; speedup vs baseline: 1.4444x; 1.4444x over previous
//
#include <hip/hip_runtime.h>

#define NBINS 100
#define NATOM 1024
#define NBLK  256
#define NWAVE 16
#define HPAD  124            // 3 under + 100 bins + 21 over: no bound checks needed
#define WIN   8              // ±4 sigma window (sigma == bin spacing); tail < 3.4e-4 rel
#define PI_F 3.14159265358979323846f

// 256 blocks x 1024 threads; block handles rows i0..i0+3, thread owns column j.
// Windowed Gaussian smear, 8 bins starting at floor(d/DB)-3 (covers -3..+4 sigma).
// Independent __expf per bin (ILP) — the exp-recurrence serial chain regressed (R5).
// Per-wave padded LDS hist -> ds_add_f32 with immediate offsets, no bound checks.
// Block partials -> ws[bin*NBLK + block]; no global atomics, no pre-zeroing.
__global__ __launch_bounds__(1024) void rdf_hist(const float* __restrict__ xyz,
                                                 const float* __restrict__ cell,
                                                 float* __restrict__ ws) {
    const float cx = cell[0], cy = cell[1], cz = cell[2];
    const float hx = 0.5f * cx, hy = 0.5f * cy, hz = 0.5f * cz;
    const float coeff  = -0.5f * (99.0f * 99.0f) / (5.0f * 5.0f);  // -196.02
    const float cutsq  = 5.5f * 5.5f;
    const float DB     = 5.0f / 99.0f;
    const float INV_DB = 99.0f / 5.0f;

    __shared__ float shw[NWAVE][HPAD];
    for (int k = threadIdx.x; k < NWAVE * HPAD; k += 1024)
        (&shw[0][0])[k] = 0.0f;
    __syncthreads();

    const int wave = threadIdx.x >> 6;

    // thread owns atom j (coalesced load)
    const int j = threadIdx.x;
    const float xj = xyz[3 * j + 0];
    const float yj = xyz[3 * j + 1];
    const float zj = xyz[3 * j + 2];

    const int i0 = blockIdx.x * (NATOM / NBLK);
#pragma unroll
    for (int r = 0; r < NATOM / NBLK; ++r) {
        const int i = i0 + r;                 // block-uniform -> scalar loads
        const float xi = xyz[3 * i + 0];
        const float yi = xyz[3 * i + 1];
        const float zi = xyz[3 * i + 2];
        float dx = xj - xi;                   // dvec = xyz[j] - xyz[i]
        float dy = yj - yi;
        float dz = zj - zi;
        // minimum-image PBC, exact replication of reference shift rule
        dx += (dx < -hx ? cx : 0.0f) - (dx >= hx ? cx : 0.0f);
        dy += (dy < -hy ? cy : 0.0f) - (dy >= hy ? cy : 0.0f);
        dz += (dz < -hz ? cz : 0.0f) - (dz >= hz ? cz : 0.0f);
        const float dsq = dx * dx + dy * dy + dz * dz;
        if (dsq != 0.0f && dsq < cutsq) {
            const float d    = sqrtf(dsq);
            const int   base = (int)(d * INV_DB) - 3;   // window [base, base+7]
            const float t0   = d - (float)base * DB;
            float* h = &shw[wave][base + 3];            // base+3 in [0, 108]
#pragma unroll
            for (int k = 0; k < WIN; ++k) {
                const float t = t0 - (float)k * DB;     // k*DB folds to a constant
                atomicAdd(&h[k], __expf(coeff * t * t));
            }
        }
    }

    __syncthreads();
    if (threadIdx.x < NBINS) {
        float s = 0.0f;
#pragma unroll
        for (int w = 0; w < NWAVE; ++w) s += shw[w][threadIdx.x + 3];
        // bin-major partial store: finalize's loads over blocks are coalesced
        ws[threadIdx.x * NBLK + blockIdx.x] = s;
    }
}

// single block, 1024 threads: reduce 256 partials/bin, normalize, emit outputs
__global__ __launch_bounds__(1024) void rdf_finalize(const float* __restrict__ ws,
                                                     float* __restrict__ out) {
    __shared__ float tot[NBINS];
    __shared__ float wsum[2];

    const int t = threadIdx.x;
    if (t < 8 * NBINS) {             // 8 threads per bin
        const int b = t >> 3, sub = t & 7;
        const float4* p = (const float4*)&ws[b * NBLK + sub * 32];
        float4 a0 = p[0], a1 = p[1], a2 = p[2], a3 = p[3];
        float4 a4 = p[4], a5 = p[5], a6 = p[6], a7 = p[7];
        float s = ((a0.x + a0.y + a0.z + a0.w) + (a1.x + a1.y + a1.z + a1.w))
                + ((a2.x + a2.y + a2.z + a2.w) + (a3.x + a3.y + a3.z + a3.w))
                + ((a4.x + a4.y + a4.z + a4.w) + (a5.x + a5.y + a5.z + a5.w))
                + ((a6.x + a6.y + a6.z + a6.w) + (a7.x + a7.y + a7.z + a7.w));
        s += __shfl_xor(s, 1, 64);   // butterfly within the 8-lane group
        s += __shfl_xor(s, 2, 64);
        s += __shfl_xor(s, 4, 64);
        if (sub == 0) tot[b] = s;
    }
    __syncthreads();

    const float v = (t < NBINS) ? tot[t] : 0.0f;
    if (t < 128) {
        float s = v;
        s += __shfl_xor(s, 1, 64);
        s += __shfl_xor(s, 2, 64);
        s += __shfl_xor(s, 4, 64);
        s += __shfl_xor(s, 8, 64);
        s += __shfl_xor(s, 16, 64);
        s += __shfl_xor(s, 32, 64);
        if ((t & 63) == 0) wsum[t >> 6] = s;
    }
    __syncthreads();
    const float total = wsum[0] + wsum[1];

    if (t < NBINS) {
        const float count = v / total;
        out[t] = count;                                   // output 0: count[100]
        const float b0 = 0.05f * (float)t;
        const float b1 = 0.05f * (float)(t + 1);
        const float vol = (4.0f * PI_F / 3.0f) * (b1 * b1 * b1 - b0 * b0 * b0);
        const float V = (4.0f / 3.0f) * PI_F * 125.0f;    // end^3 = 5^3
        out[2 * NBINS + 1 + t] = count * V / vol;         // output 2: rdf[100]
    }
    if (t < NBINS + 1) {
        out[NBINS + t] = 0.05f * (float)t;                // output 1: bins[101]
    }
}

extern "C" void kernel_launch(void* const* d_in, const int* in_sizes, int n_in,
                              void* d_out, int out_size, void* d_ws, size_t ws_size,
                              hipStream_t stream) {
    const float* xyz  = (const float*)d_in[0];
    const float* cell = (const float*)d_in[1];
    float* out = (float*)d_out;
    float* ws  = (float*)d_ws;

    rdf_hist<<<NBLK, 1024, 0, stream>>>(xyz, cell, ws);
    rdf_finalize<<<1, 1024, 0, stream>>>(ws, out);
}